// Round 1
// baseline (594.150 us; speedup 1.0000x reference)
//
#include <hip/hip_runtime.h>
#include <hip/hip_bf16.h>

#define NN 8192
#define DD 128

typedef __attribute__((ext_vector_type(4))) float f32x4;
typedef __attribute__((ext_vector_type(8))) short s16x8;

__device__ inline short bfbits(float f) {
    // fp32 -> bf16 (RNE) bit pattern
    unsigned u = __builtin_bit_cast(unsigned, f);
    u += 0x7fffu + ((u >> 16) & 1u);
    return (short)(u >> 16);
}

__device__ inline s16x8 cvt8(f32x4 a, f32x4 b) {
    s16x8 r;
    r[0] = bfbits(a[0]); r[1] = bfbits(a[1]); r[2] = bfbits(a[2]); r[3] = bfbits(a[3]);
    r[4] = bfbits(b[0]); r[5] = bfbits(b[1]); r[6] = bfbits(b[2]); r[7] = bfbits(b[3]);
    return r;
}

// -------- Kernel 1: row degree + dinv --------
// one wave per row; 268 MB streaming read, BW-bound (~43 us floor)
__global__ __launch_bounds__(256) void deg_kernel(const float* __restrict__ adj,
                                                  float* __restrict__ dinv) {
    const int lane = threadIdx.x & 63;
    const int row  = (blockIdx.x << 2) + (threadIdx.x >> 6);
    const float* r = adj + (size_t)row * NN;

    f32x4 s = {0.f, 0.f, 0.f, 0.f};
    #pragma unroll 4
    for (int it = 0; it < 32; ++it) {
        f32x4 v = *(const f32x4*)(r + it * 256 + (lane << 2));
        s += v;
    }
    float sum = s[0] + s[1] + s[2] + s[3];
    #pragma unroll
    for (int off = 32; off; off >>= 1) sum += __shfl_xor(sum, off, 64);
    if (lane == 0) dinv[row] = (sum > 0.f) ? rsqrtf(sum) : 0.f;
}

// -------- Kernel 2: h2t[n][j] = dinv[j] * (x @ W)[j][n], bf16, transposed --------
// block = 16 j-rows x 128 n; 4 waves each 16x32 (2 MFMA accumulators); K=128
__global__ __launch_bounds__(256) void proj_kernel(const float* __restrict__ x,
                                                   const float* __restrict__ w,
                                                   const float* __restrict__ dinv,
                                                   unsigned short* __restrict__ h2t) {
    const int lane = threadIdx.x & 63;
    const int wave = threadIdx.x >> 6;
    const int j0   = blockIdx.x << 4;
    const int n0   = wave << 5;
    const int r    = lane & 15;
    const int quad = lane >> 4;

    const float* xp = x + (size_t)(j0 + r) * DD + (quad << 3);

    f32x4 acc0 = {0.f, 0.f, 0.f, 0.f};
    f32x4 acc1 = {0.f, 0.f, 0.f, 0.f};

    #pragma unroll
    for (int k = 0; k < DD; k += 32) {
        f32x4 a0 = *(const f32x4*)(xp + k);
        f32x4 a1 = *(const f32x4*)(xp + k + 4);
        s16x8 af = cvt8(a0, a1);

        const int kb = k + (quad << 3);
        s16x8 b0, b1;
        #pragma unroll
        for (int j = 0; j < 8; ++j) {
            b0[j] = bfbits(w[(size_t)(kb + j) * DD + n0 + r]);
            b1[j] = bfbits(w[(size_t)(kb + j) * DD + n0 + 16 + r]);
        }
        acc0 = __builtin_amdgcn_mfma_f32_16x16x32_bf16(af, b0, acc0, 0, 0, 0);
        acc1 = __builtin_amdgcn_mfma_f32_16x16x32_bf16(af, b1, acc1, 0, 0, 0);
    }

    // C/D layout: col = lane&15 (n), row = quad*4 + reg (j)
    #pragma unroll
    for (int rr = 0; rr < 4; ++rr) {
        const int j = j0 + (quad << 2) + rr;
        const float dv = dinv[j];
        h2t[(size_t)(n0 + r) * NN + j]      = (unsigned short)bfbits(acc0[rr] * dv);
        h2t[(size_t)(n0 + 16 + r) * NN + j] = (unsigned short)bfbits(acc1[rr] * dv);
    }
}

// -------- Kernel 3: out[i][n] = dinv[i] * sum_j adj[i][j]*h2[j][n] + bias[n] --------
// block = 16 i-rows x 128 n; 4 waves each 16x32 (2 accumulators); K-loop 8192.
// adj read fp32 from HBM (268 MB, the roofline term), converted to bf16 in-register.
// B fragments are contiguous 16B loads from transposed h2t (L2-resident, 2 MB).
__global__ __launch_bounds__(256) void agg_kernel(const float* __restrict__ adj,
                                                  const unsigned short* __restrict__ h2t,
                                                  const float* __restrict__ dinv,
                                                  const float* __restrict__ bias,
                                                  float* __restrict__ out) {
    const int lane = threadIdx.x & 63;
    const int wave = threadIdx.x >> 6;
    const int m0   = blockIdx.x << 4;
    const int n0   = wave << 5;
    const int r    = lane & 15;
    const int quad = lane >> 4;

    const float* ap  = adj + (size_t)(m0 + r) * NN + (quad << 3);
    const short* bp0 = (const short*)h2t + (size_t)(n0 + r) * NN + (quad << 3);
    const short* bp1 = bp0 + (size_t)16 * NN;

    f32x4 acc0 = {0.f, 0.f, 0.f, 0.f};
    f32x4 acc1 = {0.f, 0.f, 0.f, 0.f};

    #pragma unroll 4
    for (int k = 0; k < NN; k += 32) {
        f32x4 a0 = *(const f32x4*)(ap + k);
        f32x4 a1 = *(const f32x4*)(ap + k + 4);
        s16x8 b0 = *(const s16x8*)(bp0 + k);
        s16x8 b1 = *(const s16x8*)(bp1 + k);
        s16x8 af = cvt8(a0, a1);
        acc0 = __builtin_amdgcn_mfma_f32_16x16x32_bf16(af, b0, acc0, 0, 0, 0);
        acc1 = __builtin_amdgcn_mfma_f32_16x16x32_bf16(af, b1, acc1, 0, 0, 0);
    }

    // C/D layout: col = lane&15 (n), row = quad*4 + reg (i)
    #pragma unroll
    for (int rr = 0; rr < 4; ++rr) {
        const int m = m0 + (quad << 2) + rr;
        const float dv = dinv[m];
        const int na = n0 + r;
        out[(size_t)m * DD + na]      = acc0[rr] * dv + bias[na];
        out[(size_t)m * DD + na + 16] = acc1[rr] * dv + bias[na + 16];
    }
}

extern "C" void kernel_launch(void* const* d_in, const int* in_sizes, int n_in,
                              void* d_out, int out_size, void* d_ws, size_t ws_size,
                              hipStream_t stream) {
    const float* x    = (const float*)d_in[0];   // [8192][128]
    const float* adj  = (const float*)d_in[1];   // [8192][8192]
    const float* w    = (const float*)d_in[2];   // [128][128]
    const float* bias = (const float*)d_in[3];   // [128]
    float* out = (float*)d_out;                  // [8192][128]

    // workspace layout: dinv (32 KB) | h2t bf16 [128][8192] (2 MB)
    float* dinv = (float*)d_ws;
    unsigned short* h2t = (unsigned short*)((char*)d_ws + NN * sizeof(float));

    deg_kernel<<<NN / 4, 256, 0, stream>>>(adj, dinv);
    proj_kernel<<<NN / 16, 256, 0, stream>>>(x, w, dinv, h2t);
    agg_kernel<<<NN / 16, 256, 0, stream>>>(adj, h2t, dinv, bias, out);
}

// Round 2
// 442.580 us; speedup vs baseline: 1.3425x; 1.3425x over previous
//
#include <hip/hip_runtime.h>
#include <hip/hip_bf16.h>

#define NN 8192
#define DD 128

typedef __attribute__((ext_vector_type(4))) float f32x4;
typedef __attribute__((ext_vector_type(8))) short s16x8;
typedef __attribute__((ext_vector_type(4))) short s16x4;

__device__ inline short bfbits(float f) {
    // fp32 -> bf16 (RNE) bit pattern
    unsigned u = __builtin_bit_cast(unsigned, f);
    u += 0x7fffu + ((u >> 16) & 1u);
    return (short)(u >> 16);
}

__device__ inline s16x4 cvt4(f32x4 a) {
    s16x4 r;
    r[0] = bfbits(a[0]); r[1] = bfbits(a[1]); r[2] = bfbits(a[2]); r[3] = bfbits(a[3]);
    return r;
}

__device__ inline s16x8 cvt8(f32x4 a, f32x4 b) {
    s16x8 r;
    r[0] = bfbits(a[0]); r[1] = bfbits(a[1]); r[2] = bfbits(a[2]); r[3] = bfbits(a[3]);
    r[4] = bfbits(b[0]); r[5] = bfbits(b[1]); r[6] = bfbits(b[2]); r[7] = bfbits(b[3]);
    return r;
}

// -------- Kernel 1: row degree + dinv (unchanged; streaming, coalesced) --------
__global__ __launch_bounds__(256) void deg_kernel(const float* __restrict__ adj,
                                                  float* __restrict__ dinv) {
    const int lane = threadIdx.x & 63;
    const int row  = (blockIdx.x << 2) + (threadIdx.x >> 6);
    const float* r = adj + (size_t)row * NN;

    f32x4 s = {0.f, 0.f, 0.f, 0.f};
    #pragma unroll 4
    for (int it = 0; it < 32; ++it) {
        f32x4 v = *(const f32x4*)(r + it * 256 + (lane << 2));
        s += v;
    }
    float sum = s[0] + s[1] + s[2] + s[3];
    #pragma unroll
    for (int off = 32; off; off >>= 1) sum += __shfl_xor(sum, off, 64);
    if (lane == 0) dinv[row] = (sum > 0.f) ? rsqrtf(sum) : 0.f;
}

// -------- Kernel 2: h2f = dinv[j]*(x@W)[j][n] stored in MFMA B-fragment order ----
// h2f element layout: [frag f = n>>4][kgrp = j>>5][lane = ((j>>3)&3)*16 + (n&15)][jj = j&7]
// so agg's B-load per wave is one contiguous 1 KB region per (f, kgrp).
#define WST 132  // LDS stride (shorts) for w tile: kills 8-way bank conflicts
__global__ __launch_bounds__(256) void proj_kernel(const float* __restrict__ x,
                                                   const float* __restrict__ w,
                                                   const float* __restrict__ dinv,
                                                   unsigned short* __restrict__ h2f) {
    __shared__ short lds_w[128 * WST];
    const int tid  = threadIdx.x;
    const int lane = tid & 63;
    const int wave = tid >> 6;
    const int j0   = blockIdx.x << 4;
    const int n0   = wave << 5;
    const int r    = lane & 15;
    const int q    = lane >> 4;

    // stage W -> LDS bf16, coalesced f32x4
    #pragma unroll
    for (int i = 0; i < 16; ++i) {
        int gi = i * 256 + tid;
        int k  = gi >> 5;
        int n4 = (gi & 31) << 2;
        f32x4 v = *(const f32x4*)(w + (size_t)k * DD + n4);
        *(s16x4*)&lds_w[k * WST + n4] = cvt4(v);
    }
    __syncthreads();

    const float* xp = x + (size_t)(j0 + r) * DD + (q << 3);

    f32x4 acc0 = {0.f, 0.f, 0.f, 0.f};
    f32x4 acc1 = {0.f, 0.f, 0.f, 0.f};

    #pragma unroll
    for (int k = 0; k < DD; k += 32) {
        f32x4 a0 = *(const f32x4*)(xp + k);
        f32x4 a1 = *(const f32x4*)(xp + k + 4);
        s16x8 af = cvt8(a0, a1);

        const int kb = k + (q << 3);
        s16x8 b0, b1;
        #pragma unroll
        for (int jj = 0; jj < 8; ++jj) {
            b0[jj] = lds_w[(kb + jj) * WST + n0 + r];
            b1[jj] = lds_w[(kb + jj) * WST + n0 + 16 + r];
        }
        acc0 = __builtin_amdgcn_mfma_f32_16x16x32_bf16(af, b0, acc0, 0, 0, 0);
        acc1 = __builtin_amdgcn_mfma_f32_16x16x32_bf16(af, b1, acc1, 0, 0, 0);
    }

    // C/D: col = lane&15 (n), row = q*4+rr (j). Scatter into fragment order.
    #pragma unroll
    for (int rr = 0; rr < 4; ++rr) {
        const int j = j0 + (q << 2) + rr;
        const float dv = dinv[j];
        const int kg = j >> 5, qp = (j >> 3) & 3, jj = j & 7;
        #pragma unroll
        for (int half = 0; half < 2; ++half) {
            const int n = n0 + half * 16 + r;
            const int f = n >> 4;
            const int lanep = qp * 16 + (n & 15);
            const float v = (half ? acc1[rr] : acc0[rr]) * dv;
            h2f[((((size_t)f << 8) + kg) << 6 | lanep) * 8 + jj] = (unsigned short)bfbits(v);
        }
    }
}

// -------- Kernel 3: partial[m][n] = sum_{k in split} adj[m][k]*h2[k][n] --------
// LDS-staged A (bf16, XOR-swizzled chunks, double-buffered), fragment-order B loads.
template <int KSPLIT>
__global__ __launch_bounds__(256, 4) void agg_kernel(const float* __restrict__ adj,
                                                     const unsigned short* __restrict__ h2f,
                                                     const float* __restrict__ dinv,
                                                     const float* __restrict__ bias,
                                                     float* __restrict__ dst) {
    constexpr int KS    = NN / KSPLIT;
    constexpr int TILES = KS / 128;
    __shared__ short lds_a[2][16 * 16 * 8];  // 2 x 4 KB: [buf][slot*8 shorts]

    const int tid  = threadIdx.x;
    const int lane = tid & 63;
    const int wave = tid >> 6;
    const int r    = lane & 15;
    const int q    = lane >> 4;
    const int m0   = blockIdx.x << 4;
    const int k0   = blockIdx.y * KS;

    // staging: thread covers rows (tid>>5) and 8+(tid>>5), floats (tid&31)*4..+4
    const int row0 = tid >> 5;
    const int off0 = (tid & 31) << 2;
    const int cd   = (tid & 31) >> 1;   // dest 16B chunk (8 bf16)
    const int hh   = tid & 1;           // which half of the chunk
    const int so0  = ((row0 << 4) + (cd ^ row0)) * 8 + hh * 4;
    const int so1  = (((8 + row0) << 4) + (cd ^ (8 + row0))) * 8 + hh * 4;

    const float* ap0 = adj + (size_t)(m0 + row0) * NN + k0 + off0;
    const float* ap1 = adj + (size_t)(m0 + 8 + row0) * NN + k0 + off0;

    // B: frags f = wave*2, wave*2+1; contiguous 1 KB per (f, kgrp)
    const unsigned short* bb0 = h2f + (((size_t)(wave * 2)     * 256 + (k0 >> 5)) * 64 + lane) * 8;
    const unsigned short* bb1 = h2f + (((size_t)(wave * 2 + 1) * 256 + (k0 >> 5)) * 64 + lane) * 8;

    f32x4 acc0 = {0.f, 0.f, 0.f, 0.f};
    f32x4 acc1 = {0.f, 0.f, 0.f, 0.f};

    // prologue: stage tile 0
    {
        f32x4 v0 = *(const f32x4*)(ap0);
        f32x4 v1 = *(const f32x4*)(ap1);
        *(s16x4*)&lds_a[0][so0] = cvt4(v0);
        *(s16x4*)&lds_a[0][so1] = cvt4(v1);
    }
    __syncthreads();

    for (int t = 0; t < TILES; ++t) {
        const short* lcur = lds_a[t & 1];
        short* lnxt = (short*)lds_a[(t + 1) & 1];

        // B loads for this tile (L2-resident, issued first => consumed first in vmcnt FIFO)
        s16x8 br0[4], br1[4];
        #pragma unroll
        for (int s = 0; s < 4; ++s) {
            br0[s] = *(const s16x8*)(bb0 + (size_t)(t * 4 + s) * 512);
            br1[s] = *(const s16x8*)(bb1 + (size_t)(t * 4 + s) * 512);
        }
        // staging loads for next tile (HBM; consumed only after the MFMAs)
        f32x4 v0, v1;
        if (t + 1 < TILES) {
            v0 = *(const f32x4*)(ap0 + (t + 1) * 128);
            v1 = *(const f32x4*)(ap1 + (t + 1) * 128);
        }
        // compute on current tile: A frag = one swizzled ds_read_b128
        #pragma unroll
        for (int s = 0; s < 4; ++s) {
            const int slot = (r << 4) + (((s << 2) + q) ^ r);
            s16x8 af = *(const s16x8*)(lcur + slot * 8);
            acc0 = __builtin_amdgcn_mfma_f32_16x16x32_bf16(af, br0[s], acc0, 0, 0, 0);
            acc1 = __builtin_amdgcn_mfma_f32_16x16x32_bf16(af, br1[s], acc1, 0, 0, 0);
        }
        if (t + 1 < TILES) {
            *(s16x4*)(lnxt + so0) = cvt4(v0);
            *(s16x4*)(lnxt + so1) = cvt4(v1);
        }
        __syncthreads();
    }

    // C/D: col = lane&15 (n), row = q*4+rr (m)
    #pragma unroll
    for (int rr = 0; rr < 4; ++rr) {
        const int m = m0 + (q << 2) + rr;
        const int n = (wave << 5) + r;
        if (KSPLIT == 1) {
            const float dv = dinv[m];
            dst[(size_t)m * DD + n]      = acc0[rr] * dv + bias[n];
            dst[(size_t)m * DD + n + 16] = acc1[rr] * dv + bias[n + 16];
        } else {
            float* p = dst + (size_t)blockIdx.y * NN * DD;
            p[(size_t)m * DD + n]      = acc0[rr];
            p[(size_t)m * DD + n + 16] = acc1[rr];
        }
    }
}

// -------- Kernel 4: out = dinv[m]*(p0+p1) + bias (only for KSPLIT=2 path) --------
__global__ __launch_bounds__(256) void reduce_kernel(const float* __restrict__ part,
                                                     const float* __restrict__ dinv,
                                                     const float* __restrict__ bias,
                                                     float* __restrict__ out) {
    const int idx = blockIdx.x * 256 + threadIdx.x;   // f32x4 index, NN*DD/4 total
    const f32x4 a = ((const f32x4*)part)[idx];
    const f32x4 b = ((const f32x4*)part)[idx + NN * DD / 4];
    const float dv = dinv[idx >> 5];
    const f32x4 bi = *(const f32x4*)(bias + ((idx & 31) << 2));
    f32x4 s = a + b;
    f32x4 o;
    o[0] = s[0] * dv + bi[0]; o[1] = s[1] * dv + bi[1];
    o[2] = s[2] * dv + bi[2]; o[3] = s[3] * dv + bi[3];
    ((f32x4*)out)[idx] = o;
}

extern "C" void kernel_launch(void* const* d_in, const int* in_sizes, int n_in,
                              void* d_out, int out_size, void* d_ws, size_t ws_size,
                              hipStream_t stream) {
    const float* x    = (const float*)d_in[0];   // [8192][128]
    const float* adj  = (const float*)d_in[1];   // [8192][8192]
    const float* w    = (const float*)d_in[2];   // [128][128]
    const float* bias = (const float*)d_in[3];   // [128]
    float* out = (float*)d_out;                  // [8192][128]

    // ws layout: dinv (32 KB) | h2f bf16 fragment-order (2 MB) | partials (2 x 4 MB)
    float* dinv = (float*)d_ws;
    unsigned short* h2f = (unsigned short*)((char*)d_ws + 32 * 1024);
    float* part = (float*)((char*)d_ws + 32 * 1024 + 2 * 1024 * 1024);
    const size_t need2 = 32 * 1024 + 2 * 1024 * 1024 + (size_t)2 * NN * DD * sizeof(float);

    deg_kernel<<<NN / 4, 256, 0, stream>>>(adj, dinv);
    proj_kernel<<<NN / 16, 256, 0, stream>>>(x, w, dinv, h2f);

    if (ws_size >= need2) {
        agg_kernel<2><<<dim3(NN / 16, 2), 256, 0, stream>>>(adj, h2f, dinv, bias, part);
        reduce_kernel<<<NN * DD / 4 / 256, 256, 0, stream>>>(part, dinv, bias, out);
    } else {
        agg_kernel<1><<<dim3(NN / 16, 1), 256, 0, stream>>>(adj, h2f, dinv, bias, out);
    }
}